// Round 4
// baseline (660.881 us; speedup 1.0000x reference)
//
#include <hip/hip_runtime.h>
#include <stdint.h>

// ---------- constants ----------
#define NTOK   1024
#define NHEAD  8
#define DHEAD  64
#define NBATCH 8

typedef __attribute__((ext_vector_type(8)))  short bf16x8;
typedef __attribute__((ext_vector_type(4)))  float f32x4;
typedef __attribute__((ext_vector_type(16))) float f32x16;

#define GLOAD16(g, l) __builtin_amdgcn_global_load_lds( \
    (const __attribute__((address_space(1))) unsigned int*)(g), \
    (__attribute__((address_space(3))) unsigned int*)(l), 16, 0, 0)

__device__ __forceinline__ unsigned short f2bf(float f){
  union { float f; unsigned u; } v; v.f = f;
  unsigned r = v.u + 0x7FFFu + ((v.u >> 16) & 1u);
  return (unsigned short)(r >> 16);
}
__device__ __forceinline__ float bf2f(unsigned short u){
  union { unsigned u; float f; } v; v.u = ((unsigned)u) << 16;
  return v.f;
}

// ---------- ws layout (bytes) ----------
#define WS_XB   0u          // x bf16            [8192][512]      8,388,608
#define WS_WQT  8388608u    // w_qkv^T bf16      [1536][512]      1,572,864
#define WS_WOT  9961472u    // w_out^T bf16      [512][512]         524,288
#define WS_QB   10485760u   // Q bf16            [64][1024][64]   8,388,608
#define WS_KB   18874368u   // K bf16            [64][1024][64]   8,388,608
#define WS_VT   27262976u   // V^T bf16          [64][64][1024]   8,388,608
#define WS_BIAS 35651584u   // bias bf16         [8][1024][1024] 16,777,216
#define WS_OA   52428800u   // out_attn bf16     [8][1024][512]   8,388,608
// total 60,817,408 bytes

// ================= prep: convert x, transpose+convert weights =================
__global__ void prep_kernel(const float* __restrict__ x, const float* __restrict__ wq,
                            const float* __restrict__ wo,
                            unsigned short* __restrict__ xb, unsigned short* __restrict__ wqt,
                            unsigned short* __restrict__ wot)
{
  int i = blockIdx.x * 256 + threadIdx.x;
  if (i < 1048576) {                       // x: 4,194,304 f32 as float4
    float4 v = ((const float4*)x)[i];
    ushort4 o;
    o.x = f2bf(v.x); o.y = f2bf(v.y); o.z = f2bf(v.z); o.w = f2bf(v.w);
    ((ushort4*)xb)[i] = o;
  } else if (i < 1048576 + 786432) {       // w_qkv [512][1536] -> [1536][512]
    int j = i - 1048576;
    int k = j / 1536, n = j - k * 1536;
    wqt[n * 512 + k] = f2bf(wq[j]);
  } else {                                 // w_out [512][512] -> [512][512]^T
    int j = i - (1048576 + 786432);
    int k = j >> 9, n = j & 511;
    wot[n * 512 + k] = f2bf(wo[j]);
  }
}

// ================= bias: rpb_table[rpi] + 0.01*exp(-factor*dis), bf16 =========
__global__ void bias_kernel(const float* __restrict__ rpb, const float* __restrict__ sita,
                            const float* __restrict__ dis, const int* __restrict__ rpi,
                            unsigned short* __restrict__ biasb)
{
  int i0 = blockIdx.x * 256 + threadIdx.x;
#pragma unroll
  for (int it = 0; it < 4; it++) {
    int i = i0 + it * 2097152;             // 8,388,608 total
    int h  = i >> 20;
    int ij = i & 1048575;
    float s = sita[h];
    float factor = 1.f / (2.f * s * s + 1e-10f);
    float bv = rpb[rpi[ij] * 8 + h] + 0.01f * __expf(-factor * dis[ij]);
    biasb[i] = f2bf(bv);
  }
}

// ================= qkv GEMM: [8192x512]x[512x1536], fused epilogue ============
__global__ __launch_bounds__(256) void qkv_gemm(
    const unsigned short* __restrict__ A,    // x bf16 [8192][512]
    const unsigned short* __restrict__ Bt,   // wqkv^T bf16 [1536][512]
    float* __restrict__ qkvcat,              // [b][h][n][192] f32
    unsigned short* __restrict__ qo,         // [bh][n][64]
    unsigned short* __restrict__ ko,         // [bh][n][64]
    unsigned short* __restrict__ vto)        // [bh][64][1024]
{
  __shared__ __align__(16) unsigned short As[2][128 * 32];
  __shared__ __align__(16) unsigned short Bs[2][128 * 32];
  int tid = threadIdx.x, lane = tid & 63, w = tid >> 6;
  int bm = blockIdx.x & 63, bn = blockIdx.x >> 6;     // 64 x 12
  int M0 = bm * 128, N0 = bn * 128;
  int srow = tid >> 2, scb = (tid & 3) * 8;           // staging row / col-elem

  f32x4 acc[4][4];
#pragma unroll
  for (int i = 0; i < 4; i++)
#pragma unroll
    for (int j = 0; j < 4; j++)
#pragma unroll
      for (int p = 0; p < 4; p++) acc[i][j][p] = 0.f;

#pragma unroll
  for (int r = 0; r < 2; r++) {
    GLOAD16(A  + ((size_t)(M0 + r * 64 + srow) * 512 + scb), &As[0][(r * 64 + srow) * 32 + scb]);
    GLOAD16(Bt + ((size_t)(N0 + r * 64 + srow) * 512 + scb), &Bs[0][(r * 64 + srow) * 32 + scb]);
  }
  int wr = w >> 1, wc = w & 1, l16 = lane & 15, l8 = (lane >> 4) * 8;

  for (int kt = 0; kt < 16; kt++) {
    __syncthreads();
    int cur = kt & 1;
    if (kt < 15) {
      int nb = cur ^ 1, ko2 = (kt + 1) * 32;
#pragma unroll
      for (int r = 0; r < 2; r++) {
        GLOAD16(A  + ((size_t)(M0 + r * 64 + srow) * 512 + ko2 + scb), &As[nb][(r * 64 + srow) * 32 + scb]);
        GLOAD16(Bt + ((size_t)(N0 + r * 64 + srow) * 512 + ko2 + scb), &Bs[nb][(r * 64 + srow) * 32 + scb]);
      }
    }
    bf16x8 af[4], bfr[4];
#pragma unroll
    for (int i = 0; i < 4; i++) af[i]  = *(const bf16x8*)&As[cur][(wr * 64 + i * 16 + l16) * 32 + l8];
#pragma unroll
    for (int j = 0; j < 4; j++) bfr[j] = *(const bf16x8*)&Bs[cur][(wc * 64 + j * 16 + l16) * 32 + l8];
#pragma unroll
    for (int i = 0; i < 4; i++)
#pragma unroll
      for (int j = 0; j < 4; j++)
        acc[i][j] = __builtin_amdgcn_mfma_f32_16x16x32_bf16(af[i], bfr[j], acc[i][j], 0, 0, 0);
  }

  // epilogue: write f32 qkv_cat + bf16 Q/K + bf16 V^T
#pragma unroll
  for (int i = 0; i < 4; i++) {
    int rbase = M0 + wr * 64 + i * 16 + (lane >> 4) * 4;
#pragma unroll
    for (int j = 0; j < 4; j++) {
      int col = N0 + wc * 64 + j * 16 + l16;
      int s = col >> 9, hh = (col >> 6) & 7, d = col & 63;
#pragma unroll
      for (int p = 0; p < 4; p++) {
        int row = rbase + p;
        int b = row >> 10, n = row & 1023;
        float v = acc[i][j][p];
        size_t hn = (size_t)((b * 8 + hh) * 1024 + n);
        qkvcat[hn * 192 + s * 64 + d] = v;
        unsigned short bv = f2bf(v);
        if (s == 0)      qo[hn * 64 + d] = bv;
        else if (s == 1) ko[hn * 64 + d] = bv;
        else             vto[((size_t)((b * 8 + hh) * 64 + d)) * 1024 + n] = bv;
      }
    }
  }
}

// ================= attention: QK^T, dual softmax, softmax0 write, PV ==========
#define ATTN_SMEM (131072 + 2048 + 768)

__global__ __launch_bounds__(512, 2) void attn_kernel(
    const unsigned short* __restrict__ qb,   // [bh][1024][64]
    const unsigned short* __restrict__ kb,   // [bh][1024][64]
    const unsigned short* __restrict__ vtb,  // [bh][64][1024]
    const unsigned short* __restrict__ biasb,// [8][1024][1024]
    float* __restrict__ sm0,                 // [bh][1024][1024]
    unsigned short* __restrict__ oa)         // [b][1024][512]
{
  extern __shared__ char smem[];
  unsigned short* Plds = (unsigned short*)smem;          // [64][1024] bf16, XOR-swizzled
  float* red = (float*)(smem + 131072);                  // 512 f32 scratch
  float* fin = red + 512;                                // m0[64], inv0[64], invb[64]

  int tid = threadIdx.x, lane = tid & 63, w = tid >> 6;
  int rw = w >> 2, cw = w & 3;                           // QK wave grid 2x4
  int hi = lane >> 5, ln = lane & 31;
  int blk = blockIdx.x;
  int rt = blk & 15, bh = blk >> 4;
  int h = bh & 7;
  int row0 = rt * 64;
  size_t qkvbase = (size_t)bh * (NTOK * DHEAD);

  // ---- Q fragments (4 k-steps of 16) ----
  bf16x8 qf[4];
  {
    int qrow = row0 + 32 * rw + ln;
    const unsigned short* qp = qb + qkvbase + (size_t)qrow * 64 + hi * 8;
#pragma unroll
    for (int ks = 0; ks < 4; ks++) qf[ks] = *(const bf16x8*)(qp + ks * 16);
  }

  // ---- QK^T into 8 tiles of 32x32 ----
  f32x16 acc[8];
#pragma unroll
  for (int t = 0; t < 8; t++)
#pragma unroll
    for (int r = 0; r < 16; r++) acc[t][r] = 0.f;

#pragma unroll
  for (int t = 0; t < 8; t++) {
    int kcol = 256 * cw + 32 * t + ln;
    const unsigned short* kp = kb + qkvbase + (size_t)kcol * 64 + hi * 8;
#pragma unroll
    for (int ks = 0; ks < 4; ks++) {
      bf16x8 kf = *(const bf16x8*)(kp + ks * 16);
      acc[t] = __builtin_amdgcn_mfma_f32_32x32x16_bf16(qf[ks], kf, acc[t], 0, 0, 0);
    }
  }
#pragma unroll
  for (int t = 0; t < 8; t++)
#pragma unroll
    for (int r = 0; r < 16; r++) acc[t][r] *= 0.125f;    // DIM_HEAD^-0.5

  // ---- pass 1: shared row max (serves both softmaxes; shift-invariant) ----
#pragma unroll
  for (int r = 0; r < 16; r++) {
    float m = acc[0][r];
#pragma unroll
    for (int t = 1; t < 8; t++) m = fmaxf(m, acc[t][r]);
#pragma unroll
    for (int msk = 1; msk < 32; msk <<= 1) m = fmaxf(m, __shfl_xor(m, msk));
    if (ln == r) red[(32 * rw + (r & 3) + 8 * (r >> 2) + 4 * hi) * 4 + cw] = m;
  }
  __syncthreads();
  if (tid < 64)
    fin[tid] = fmaxf(fmaxf(red[tid * 4], red[tid * 4 + 1]),
                     fmaxf(red[tid * 4 + 2], red[tid * 4 + 3]));
  __syncthreads();

  // ---- pass 2: sums for both softmaxes; stage P=exp(S+bias-m) in LDS ----
  float m0r[16];
#pragma unroll
  for (int r = 0; r < 16; r++) m0r[r] = fin[32 * rw + (r & 3) + 8 * (r >> 2) + 4 * hi];
  float s0[16], sb[16];
#pragma unroll
  for (int r = 0; r < 16; r++) { s0[r] = 0.f; sb[r] = 0.f; }

#pragma unroll
  for (int t = 0; t < 8; t++) {
    int col = 256 * cw + 32 * t + ln;
    const unsigned short* bp = biasb + ((size_t)h << 20) + ((size_t)row0 << 10) + col;
#pragma unroll
    for (int r = 0; r < 16; r++) {
      int rl = 32 * rw + (r & 3) + 8 * (r >> 2) + 4 * hi;
      float bv = bf2f(bp[(size_t)rl << 10]);
      float e0 = __expf(acc[t][r] - m0r[r]);
      float eb = __expf(acc[t][r] + bv - m0r[r]);
      s0[r] += e0; sb[r] += eb;
      unsigned byteoff = (((unsigned)rl << 11) + ((unsigned)col << 1)) ^ ((unsigned)(rl & 7) << 4);
      *(unsigned short*)((char*)Plds + byteoff) = f2bf(eb);
    }
  }
#pragma unroll
  for (int r = 0; r < 16; r++) {
    float a0 = s0[r], ab = sb[r];
#pragma unroll
    for (int msk = 1; msk < 32; msk <<= 1) { a0 += __shfl_xor(a0, msk); ab += __shfl_xor(ab, msk); }
    if (ln == r) {
      int rl = 32 * rw + (r & 3) + 8 * (r >> 2) + 4 * hi;
      red[(rl * 4 + cw) * 2]     = a0;
      red[(rl * 4 + cw) * 2 + 1] = ab;
    }
  }
  __syncthreads();
  if (tid < 64) {
    float a0 = red[tid * 8] + red[tid * 8 + 2] + red[tid * 8 + 4] + red[tid * 8 + 6];
    float ab = red[tid * 8 + 1] + red[tid * 8 + 3] + red[tid * 8 + 5] + red[tid * 8 + 7];
    fin[64 + tid]  = 1.f / a0;
    fin[128 + tid] = 1.f / ab;
  }
  __syncthreads();

  // ---- pass 3: write softmax(dots0) ----
  float i0r[16];
#pragma unroll
  for (int r = 0; r < 16; r++) i0r[r] = fin[64 + 32 * rw + (r & 3) + 8 * (r >> 2) + 4 * hi];
  size_t obase = ((size_t)bh << 20) + ((size_t)row0 << 10);
#pragma unroll
  for (int t = 0; t < 8; t++) {
    int col = 256 * cw + 32 * t + ln;
#pragma unroll
    for (int r = 0; r < 16; r++) {
      int rl = 32 * rw + (r & 3) + 8 * (r >> 2) + 4 * hi;
      float e0 = __expf(acc[t][r] - m0r[r]);
      sm0[obase + ((size_t)rl << 10) + col] = e0 * i0r[r];
    }
  }

  // ---- PV: out[64x64] via 16x16x32; wave w -> n-tile w>>1, m-tiles {2*(w&1),+1}
  int l4 = lane >> 4, l16 = lane & 15;
  int dcol = (w >> 1) * 16 + l16;
  const unsigned short* vp = vtb + qkvbase + (size_t)dcol * 1024 + l4 * 8;
  f32x4 av[2];
#pragma unroll
  for (int im = 0; im < 2; im++)
#pragma unroll
    for (int p = 0; p < 4; p++) av[im][p] = 0.f;

  for (int ks = 0; ks < 32; ks++) {
    bf16x8 vf = *(const bf16x8*)(vp + ks * 32);
#pragma unroll
    for (int im = 0; im < 2; im++) {
      int prow = (2 * (w & 1) + im) * 16 + l16;
      unsigned byteoff = (((unsigned)prow << 11) + (unsigned)(ks * 64 + l4 * 16)) ^ ((unsigned)(prow & 7) << 4);
      bf16x8 pf = *(const bf16x8*)((char*)Plds + byteoff);
      av[im] = __builtin_amdgcn_mfma_f32_16x16x32_bf16(pf, vf, av[im], 0, 0, 0);
    }
  }

  int b = bh >> 3;
#pragma unroll
  for (int im = 0; im < 2; im++) {
    int mt = 2 * (w & 1) + im;
#pragma unroll
    for (int p = 0; p < 4; p++) {
      int rl = mt * 16 + l4 * 4 + p;
      float o = av[im][p] * fin[128 + rl];
      int n = row0 + rl;
      oa[(size_t)(b * 1024 + n) * 512 + h * 64 + dcol] = f2bf(o);
    }
  }
}

// ================= out GEMM: [8192x512]x[512x512] + bias ======================
__global__ __launch_bounds__(256) void out_gemm(
    const unsigned short* __restrict__ A,    // out_attn bf16 [8192][512]
    const unsigned short* __restrict__ Bt,   // w_out^T bf16 [512][512]
    const float* __restrict__ bout,          // [512]
    float* __restrict__ out)                 // [8192][512] f32
{
  __shared__ __align__(16) unsigned short As[2][128 * 32];
  __shared__ __align__(16) unsigned short Bs[2][128 * 32];
  int tid = threadIdx.x, lane = tid & 63, w = tid >> 6;
  int bm = blockIdx.x & 63, bn = blockIdx.x >> 6;     // 64 x 4
  int M0 = bm * 128, N0 = bn * 128;
  int srow = tid >> 2, scb = (tid & 3) * 8;

  f32x4 acc[4][4];
#pragma unroll
  for (int i = 0; i < 4; i++)
#pragma unroll
    for (int j = 0; j < 4; j++)
#pragma unroll
      for (int p = 0; p < 4; p++) acc[i][j][p] = 0.f;

#pragma unroll
  for (int r = 0; r < 2; r++) {
    GLOAD16(A  + ((size_t)(M0 + r * 64 + srow) * 512 + scb), &As[0][(r * 64 + srow) * 32 + scb]);
    GLOAD16(Bt + ((size_t)(N0 + r * 64 + srow) * 512 + scb), &Bs[0][(r * 64 + srow) * 32 + scb]);
  }
  int wr = w >> 1, wc = w & 1, l16 = lane & 15, l8 = (lane >> 4) * 8;

  for (int kt = 0; kt < 16; kt++) {
    __syncthreads();
    int cur = kt & 1;
    if (kt < 15) {
      int nb = cur ^ 1, ko2 = (kt + 1) * 32;
#pragma unroll
      for (int r = 0; r < 2; r++) {
        GLOAD16(A  + ((size_t)(M0 + r * 64 + srow) * 512 + ko2 + scb), &As[nb][(r * 64 + srow) * 32 + scb]);
        GLOAD16(Bt + ((size_t)(N0 + r * 64 + srow) * 512 + ko2 + scb), &Bs[nb][(r * 64 + srow) * 32 + scb]);
      }
    }
    bf16x8 af[4], bfr[4];
#pragma unroll
    for (int i = 0; i < 4; i++) af[i]  = *(const bf16x8*)&As[cur][(wr * 64 + i * 16 + l16) * 32 + l8];
#pragma unroll
    for (int j = 0; j < 4; j++) bfr[j] = *(const bf16x8*)&Bs[cur][(wc * 64 + j * 16 + l16) * 32 + l8];
#pragma unroll
    for (int i = 0; i < 4; i++)
#pragma unroll
      for (int j = 0; j < 4; j++)
        acc[i][j] = __builtin_amdgcn_mfma_f32_16x16x32_bf16(af[i], bfr[j], acc[i][j], 0, 0, 0);
  }

#pragma unroll
  for (int i = 0; i < 4; i++) {
    int rbase = M0 + wr * 64 + i * 16 + (lane >> 4) * 4;
#pragma unroll
    for (int j = 0; j < 4; j++) {
      int col = N0 + wc * 64 + j * 16 + l16;
      float bb = bout[col];
#pragma unroll
      for (int p = 0; p < 4; p++) {
        int row = rbase + p;
        out[(size_t)row * 512 + col] = acc[i][j][p] + bb;
      }
    }
  }
}

// ================= launch =====================================================
extern "C" void kernel_launch(void* const* d_in, const int* in_sizes, int n_in,
                              void* d_out, int out_size, void* d_ws, size_t ws_size,
                              hipStream_t stream)
{
  const float* x    = (const float*)d_in[0];
  const float* wqkv = (const float*)d_in[1];
  const float* rpb  = (const float*)d_in[2];
  const float* sita = (const float*)d_in[3];
  const float* wout = (const float*)d_in[4];
  const float* bout = (const float*)d_in[5];
  const float* dis  = (const float*)d_in[6];
  const int*   rpi  = (const int*)d_in[7];

  float* out    = (float*)d_out;                 // [8,1024,512]
  float* qkvcat = out + 4194304;                 // [8,8,1024,192]
  float* sm0    = out + 16777216;                // [8,8,1024,1024]

  char* ws = (char*)d_ws;
  unsigned short* xb   = (unsigned short*)(ws + WS_XB);
  unsigned short* wqt  = (unsigned short*)(ws + WS_WQT);
  unsigned short* wot  = (unsigned short*)(ws + WS_WOT);
  unsigned short* qbp  = (unsigned short*)(ws + WS_QB);
  unsigned short* kbp  = (unsigned short*)(ws + WS_KB);
  unsigned short* vtp  = (unsigned short*)(ws + WS_VT);
  unsigned short* bias = (unsigned short*)(ws + WS_BIAS);
  unsigned short* oa   = (unsigned short*)(ws + WS_OA);

  prep_kernel<<<8192, 256, 0, stream>>>(x, wqkv, wout, xb, wqt, wot);
  bias_kernel<<<8192, 256, 0, stream>>>(rpb, sita, dis, rpi, bias);
  qkv_gemm<<<768, 256, 0, stream>>>(xb, wqt, qkvcat, qbp, kbp, vtp);
  hipFuncSetAttribute((const void*)attn_kernel,
                      hipFuncAttributeMaxDynamicSharedMemorySize, ATTN_SMEM);
  attn_kernel<<<1024, 512, ATTN_SMEM, stream>>>(qbp, kbp, vtp, bias, sm0, oa);
  out_gemm<<<256, 256, 0, stream>>>(oa, wot, bout, out);
}

// Round 5
// 537.816 us; speedup vs baseline: 1.2288x; 1.2288x over previous
//
#include <hip/hip_runtime.h>
#include <stdint.h>

// ---------- constants ----------
#define NTOK   1024
#define NHEAD  8
#define DHEAD  64
#define NBATCH 8

typedef __attribute__((ext_vector_type(8)))  short bf16x8;
typedef __attribute__((ext_vector_type(4)))  float f32x4;
typedef __attribute__((ext_vector_type(16))) float f32x16;

#define GLOAD16(g, l) __builtin_amdgcn_global_load_lds( \
    (const __attribute__((address_space(1))) unsigned int*)(g), \
    (__attribute__((address_space(3))) unsigned int*)(l), 16, 0, 0)

__device__ __forceinline__ unsigned short f2bf(float f){
  union { float f; unsigned u; } v; v.f = f;
  unsigned r = v.u + 0x7FFFu + ((v.u >> 16) & 1u);
  return (unsigned short)(r >> 16);
}
__device__ __forceinline__ float bf2f(unsigned short u){
  union { unsigned u; float f; } v; v.u = ((unsigned)u) << 16;
  return v.f;
}

// ---------- ws layout (bytes) ----------
#define WS_XB   0u          // x bf16            [8192][512]      8,388,608
#define WS_WQT  8388608u    // w_qkv^T bf16      [1536][512]      1,572,864
#define WS_WOT  9961472u    // w_out^T bf16      [512][512]         524,288
#define WS_QB   10485760u   // Q bf16            [64][1024][64]   8,388,608
#define WS_KB   18874368u   // K bf16            [64][1024][64]   8,388,608
#define WS_VT   27262976u   // V^T bf16          [64][64][1024]   8,388,608
#define WS_BIAS 35651584u   // bias bf16         [8][1024][1024] 16,777,216
#define WS_OA   52428800u   // V row-major, then out_attn bf16   8,388,608
// total 60,817,408 bytes

// ================= prep: convert x, transpose+convert weights =================
__global__ void prep_kernel(const float* __restrict__ x, const float* __restrict__ wq,
                            const float* __restrict__ wo,
                            unsigned short* __restrict__ xb, unsigned short* __restrict__ wqt,
                            unsigned short* __restrict__ wot)
{
  int i = blockIdx.x * 256 + threadIdx.x;
  if (i < 1048576) {                       // x: 4,194,304 f32 as float4
    float4 v = ((const float4*)x)[i];
    ushort4 o;
    o.x = f2bf(v.x); o.y = f2bf(v.y); o.z = f2bf(v.z); o.w = f2bf(v.w);
    ((ushort4*)xb)[i] = o;
  } else if (i < 1048576 + 786432) {       // w_qkv [512][1536] -> [1536][512]
    int j = i - 1048576;
    int k = j / 1536, n = j - k * 1536;
    wqt[n * 512 + k] = f2bf(wq[j]);
  } else {                                 // w_out [512][512] -> [512][512]^T
    int j = i - (1048576 + 786432);
    int k = j >> 9, n = j & 511;
    wot[n * 512 + k] = f2bf(wo[j]);
  }
}

// ================= bias: rpb_table[rpi] + 0.01*exp(-factor*dis), bf16 =========
__global__ void bias_kernel(const float* __restrict__ rpb, const float* __restrict__ sita,
                            const float* __restrict__ dis, const int* __restrict__ rpi,
                            unsigned short* __restrict__ biasb)
{
  int i0 = blockIdx.x * 256 + threadIdx.x;
#pragma unroll
  for (int it = 0; it < 4; it++) {
    int i = i0 + it * 2097152;             // 8,388,608 total
    int h  = i >> 20;
    int ij = i & 1048575;
    float s = sita[h];
    float factor = 1.f / (2.f * s * s + 1e-10f);
    float bv = rpb[rpi[ij] * 8 + h] + 0.01f * __expf(-factor * dis[ij]);
    biasb[i] = f2bf(bv);
  }
}

// ================= qkv GEMM: [8192x512]x[512x1536], fused epilogue ============
__global__ __launch_bounds__(256) void qkv_gemm(
    const unsigned short* __restrict__ A,    // x bf16 [8192][512]
    const unsigned short* __restrict__ Bt,   // wqkv^T bf16 [1536][512]
    float* __restrict__ qkvcat,              // [b][h][n][192] f32
    unsigned short* __restrict__ qo,         // [bh][n][64]
    unsigned short* __restrict__ ko,         // [bh][n][64]
    unsigned short* __restrict__ vo)         // [bh][n][64] (row-major V)
{
  __shared__ __align__(16) unsigned short As[2][128 * 32];
  __shared__ __align__(16) unsigned short Bs[2][128 * 32];
  int tid = threadIdx.x, lane = tid & 63, w = tid >> 6;
  int bm = blockIdx.x & 63, bn = blockIdx.x >> 6;     // 64 x 12
  int M0 = bm * 128, N0 = bn * 128;
  int srow = tid >> 2, scb = (tid & 3) * 8;           // staging row / col-elem

  f32x4 acc[4][4];
#pragma unroll
  for (int i = 0; i < 4; i++)
#pragma unroll
    for (int j = 0; j < 4; j++)
#pragma unroll
      for (int p = 0; p < 4; p++) acc[i][j][p] = 0.f;

#pragma unroll
  for (int r = 0; r < 2; r++) {
    GLOAD16(A  + ((size_t)(M0 + r * 64 + srow) * 512 + scb), &As[0][(r * 64 + srow) * 32 + scb]);
    GLOAD16(Bt + ((size_t)(N0 + r * 64 + srow) * 512 + scb), &Bs[0][(r * 64 + srow) * 32 + scb]);
  }
  int wr = w >> 1, wc = w & 1, l16 = lane & 15, l8 = (lane >> 4) * 8;

  for (int kt = 0; kt < 16; kt++) {
    __syncthreads();
    int cur = kt & 1;
    if (kt < 15) {
      int nb = cur ^ 1, ko2 = (kt + 1) * 32;
#pragma unroll
      for (int r = 0; r < 2; r++) {
        GLOAD16(A  + ((size_t)(M0 + r * 64 + srow) * 512 + ko2 + scb), &As[nb][(r * 64 + srow) * 32 + scb]);
        GLOAD16(Bt + ((size_t)(N0 + r * 64 + srow) * 512 + ko2 + scb), &Bs[nb][(r * 64 + srow) * 32 + scb]);
      }
    }
    bf16x8 af[4], bfr[4];
#pragma unroll
    for (int i = 0; i < 4; i++) af[i]  = *(const bf16x8*)&As[cur][(wr * 64 + i * 16 + l16) * 32 + l8];
#pragma unroll
    for (int j = 0; j < 4; j++) bfr[j] = *(const bf16x8*)&Bs[cur][(wc * 64 + j * 16 + l16) * 32 + l8];
#pragma unroll
    for (int i = 0; i < 4; i++)
#pragma unroll
      for (int j = 0; j < 4; j++)
        acc[i][j] = __builtin_amdgcn_mfma_f32_16x16x32_bf16(af[i], bfr[j], acc[i][j], 0, 0, 0);
  }

  // epilogue: write f32 qkv_cat + bf16 Q/K/V (all row-major head layout)
#pragma unroll
  for (int i = 0; i < 4; i++) {
    int rbase = M0 + wr * 64 + i * 16 + (lane >> 4) * 4;
#pragma unroll
    for (int j = 0; j < 4; j++) {
      int col = N0 + wc * 64 + j * 16 + l16;
      int s = col >> 9, hh = (col >> 6) & 7, d = col & 63;
#pragma unroll
      for (int p = 0; p < 4; p++) {
        int row = rbase + p;
        int b = row >> 10, n = row & 1023;
        float v = acc[i][j][p];
        size_t hn = (size_t)((b * 8 + hh) * 1024 + n);
        qkvcat[hn * 192 + s * 64 + d] = v;
        unsigned short bv = f2bf(v);
        if (s == 0)      qo[hn * 64 + d] = bv;
        else if (s == 1) ko[hn * 64 + d] = bv;
        else             vo[hn * 64 + d] = bv;
      }
    }
  }
}

// ================= vtrans: V [bh][n][64] -> V^T [bh][64][1024] ================
__global__ __launch_bounds__(256) void vtrans_kernel(
    const unsigned short* __restrict__ vo, unsigned short* __restrict__ vto)
{
  __shared__ unsigned short t[64][65];
  int blk = blockIdx.x;                    // 64 bh x 16 nt
  int bh = blk >> 4, nt = blk & 15;
  int tid = threadIdx.x;
  const unsigned short* src = vo + (((size_t)bh * 1024 + nt * 64) << 6);
  int row = tid >> 2, c8 = (tid & 3) * 16;
  *(bf16x8*)&t[row][c8]     = *(const bf16x8*)(src + row * 64 + c8);
  *(bf16x8*)&t[row][c8 + 8] = *(const bf16x8*)(src + row * 64 + c8 + 8);
  __syncthreads();
  int d = tid >> 2, n8 = (tid & 3) * 16;
  bf16x8 o0, o1;
#pragma unroll
  for (int i = 0; i < 8; i++) { o0[i] = (short)t[n8 + i][d]; o1[i] = (short)t[n8 + 8 + i][d]; }
  unsigned short* dst = vto + ((size_t)(bh * 64 + d) << 10) + nt * 64 + n8;
  *(bf16x8*)dst       = o0;
  *(bf16x8*)(dst + 8) = o1;
}

// ================= attention: QBLK=32, 8 waves, 2 blocks/CU ===================
#define ATTN_SMEM (65536 + 2048 + 384)

__global__ __launch_bounds__(512, 4) void attn_kernel(
    const unsigned short* __restrict__ qb,   // [bh][1024][64]
    const unsigned short* __restrict__ kb,   // [bh][1024][64]
    const unsigned short* __restrict__ vtb,  // [bh][64][1024]
    const unsigned short* __restrict__ biasb,// [8][1024][1024]
    float* __restrict__ sm0,                 // [bh][1024][1024]
    unsigned short* __restrict__ oa)         // [b][1024][512]
{
  extern __shared__ char smem[];
  unsigned short* Plds = (unsigned short*)smem;          // [32][1024] bf16, XOR-swizzled
  float* red = (float*)(smem + 65536);                   // 512 f32 scratch
  float* fin = red + 512;                                // m0[32], inv0[32], invb[32]

  int tid = threadIdx.x, lane = tid & 63, w = tid >> 6;
  int hi = lane >> 5, ln = lane & 31;
  // XCD-local decode: blk%8 == bh%8 == h, so all 32 row-tiles of a bh (and its
  // h-slice of bias) stay on one XCD's L2.
  int blk = blockIdx.x;                                  // 2048 = 8 bhhi x 32 rt x 8 h
  int bh = ((blk >> 8) << 3) | (blk & 7);
  int rt = (blk >> 3) & 31;
  int h  = blk & 7;
  int row0 = rt * 32;
  size_t qkvbase = (size_t)bh << 16;                     // *1024*64

  // ---- Q fragments (4 k-steps of 16); all waves load the same 32 rows ----
  bf16x8 qf[4];
  {
    const unsigned short* qp = qb + qkvbase + (size_t)(row0 + ln) * 64 + hi * 8;
#pragma unroll
    for (int ks = 0; ks < 4; ks++) qf[ks] = *(const bf16x8*)(qp + ks * 16);
  }

  // ---- QK^T: wave w covers cols [128w,128w+128) as 4 tiles of 32x32 ----
  f32x16 acc[4];
#pragma unroll
  for (int t = 0; t < 4; t++)
#pragma unroll
    for (int r = 0; r < 16; r++) acc[t][r] = 0.f;

#pragma unroll
  for (int t = 0; t < 4; t++) {
    int kcol = w * 128 + 32 * t + ln;
    const unsigned short* kp = kb + qkvbase + (size_t)kcol * 64 + hi * 8;
#pragma unroll
    for (int ks = 0; ks < 4; ks++) {
      bf16x8 kf = *(const bf16x8*)(kp + ks * 16);
      acc[t] = __builtin_amdgcn_mfma_f32_32x32x16_bf16(qf[ks], kf, acc[t], 0, 0, 0);
    }
  }
#pragma unroll
  for (int t = 0; t < 4; t++)
#pragma unroll
    for (int r = 0; r < 16; r++) acc[t][r] *= 0.125f;    // DIM_HEAD^-0.5

  // ---- pass 1: row max (shared by both softmaxes; shift-invariant) ----
#pragma unroll
  for (int r = 0; r < 16; r++) {
    float m = fmaxf(fmaxf(acc[0][r], acc[1][r]), fmaxf(acc[2][r], acc[3][r]));
#pragma unroll
    for (int msk = 1; msk < 32; msk <<= 1) m = fmaxf(m, __shfl_xor(m, msk));
    if (ln == r) red[((r & 3) + 8 * (r >> 2) + 4 * hi) * 8 + w] = m;
  }
  __syncthreads();
  if (tid < 32) {
    float m = red[tid * 8];
#pragma unroll
    for (int j = 1; j < 8; j++) m = fmaxf(m, red[tid * 8 + j]);
    fin[tid] = m;
  }
  __syncthreads();

  // ---- pass 2: dual sums; stage P=exp(S+bias-m) bf16 in swizzled LDS ----
#pragma unroll
  for (int r = 0; r < 16; r++) {
    int rl = (r & 3) + 8 * (r >> 2) + 4 * hi;
    float m0 = fin[rl];
    const unsigned short* bp = biasb + ((size_t)h << 20) + ((size_t)(row0 + rl) << 10);
    float s0 = 0.f, sb = 0.f;
#pragma unroll
    for (int t = 0; t < 4; t++) {
      int col = w * 128 + 32 * t + ln;
      float bv = bf2f(bp[col]);
      float sv = acc[t][r];
      float e0 = __expf(sv - m0);
      float eb = __expf(sv + bv - m0);
      s0 += e0; sb += eb;
      unsigned byteoff = (((unsigned)rl << 11) + ((unsigned)col << 1)) ^ ((unsigned)(rl & 7) << 4);
      *(unsigned short*)((char*)Plds + byteoff) = f2bf(eb);
    }
#pragma unroll
    for (int msk = 1; msk < 32; msk <<= 1) { s0 += __shfl_xor(s0, msk); sb += __shfl_xor(sb, msk); }
    if (ln == r) { red[rl * 16 + w * 2] = s0; red[rl * 16 + w * 2 + 1] = sb; }
  }
  __syncthreads();
  if (tid < 32) {
    float a0 = 0.f, ab = 0.f;
#pragma unroll
    for (int j = 0; j < 8; j++) { a0 += red[tid * 16 + 2 * j]; ab += red[tid * 16 + 2 * j + 1]; }
    fin[32 + tid] = 1.f / a0;
    fin[64 + tid] = 1.f / ab;
  }
  __syncthreads();

  // ---- pass 3: write softmax(dots0) f32 ----
  size_t obase = ((size_t)bh << 20) + ((size_t)row0 << 10);
#pragma unroll
  for (int r = 0; r < 16; r++) {
    int rl = (r & 3) + 8 * (r >> 2) + 4 * hi;
    float m0 = fin[rl], i0 = fin[32 + rl];
#pragma unroll
    for (int t = 0; t < 4; t++) {
      int col = w * 128 + 32 * t + ln;
      sm0[obase + ((size_t)rl << 10) + col] = __expf(acc[t][r] - m0) * i0;
    }
  }

  // ---- PV: out[32x64]; wave w -> m-tile w&1, d-tile w>>2... (2x4 grid) ----
  int l4 = lane >> 4, l16 = lane & 15;
  int mt = w & 1, ntile = w >> 1;
  int dcol = ntile * 16 + l16;
  const unsigned short* vp = vtb + qkvbase + (size_t)dcol * 1024 + l4 * 8;
  f32x4 av;
#pragma unroll
  for (int p = 0; p < 4; p++) av[p] = 0.f;
  int prow = mt * 16 + l16;
  for (int ks = 0; ks < 32; ks++) {
    bf16x8 vf = *(const bf16x8*)(vp + ks * 32);
    unsigned byteoff = (((unsigned)prow << 11) + (unsigned)(ks * 64 + l4 * 16)) ^ ((unsigned)(prow & 7) << 4);
    bf16x8 pf = *(const bf16x8*)((char*)Plds + byteoff);
    av = __builtin_amdgcn_mfma_f32_16x16x32_bf16(pf, vf, av, 0, 0, 0);
  }

  int b = bh >> 3;
#pragma unroll
  for (int p = 0; p < 4; p++) {
    int rl = mt * 16 + l4 * 4 + p;
    float o = av[p] * fin[64 + rl];
    oa[(size_t)(b * 1024 + row0 + rl) * 512 + h * 64 + dcol] = f2bf(o);
  }
}

// ================= out GEMM: [8192x512]x[512x512] + bias ======================
__global__ __launch_bounds__(256) void out_gemm(
    const unsigned short* __restrict__ A,    // out_attn bf16 [8192][512]
    const unsigned short* __restrict__ Bt,   // w_out^T bf16 [512][512]
    const float* __restrict__ bout,          // [512]
    float* __restrict__ out)                 // [8192][512] f32
{
  __shared__ __align__(16) unsigned short As[2][128 * 32];
  __shared__ __align__(16) unsigned short Bs[2][128 * 32];
  int tid = threadIdx.x, lane = tid & 63, w = tid >> 6;
  int bm = blockIdx.x & 63, bn = blockIdx.x >> 6;     // 64 x 4
  int M0 = bm * 128, N0 = bn * 128;
  int srow = tid >> 2, scb = (tid & 3) * 8;

  f32x4 acc[4][4];
#pragma unroll
  for (int i = 0; i < 4; i++)
#pragma unroll
    for (int j = 0; j < 4; j++)
#pragma unroll
      for (int p = 0; p < 4; p++) acc[i][j][p] = 0.f;

#pragma unroll
  for (int r = 0; r < 2; r++) {
    GLOAD16(A  + ((size_t)(M0 + r * 64 + srow) * 512 + scb), &As[0][(r * 64 + srow) * 32 + scb]);
    GLOAD16(Bt + ((size_t)(N0 + r * 64 + srow) * 512 + scb), &Bs[0][(r * 64 + srow) * 32 + scb]);
  }
  int wr = w >> 1, wc = w & 1, l16 = lane & 15, l8 = (lane >> 4) * 8;

  for (int kt = 0; kt < 16; kt++) {
    __syncthreads();
    int cur = kt & 1;
    if (kt < 15) {
      int nb = cur ^ 1, ko2 = (kt + 1) * 32;
#pragma unroll
      for (int r = 0; r < 2; r++) {
        GLOAD16(A  + ((size_t)(M0 + r * 64 + srow) * 512 + ko2 + scb), &As[nb][(r * 64 + srow) * 32 + scb]);
        GLOAD16(Bt + ((size_t)(N0 + r * 64 + srow) * 512 + ko2 + scb), &Bs[nb][(r * 64 + srow) * 32 + scb]);
      }
    }
    bf16x8 af[4], bfr[4];
#pragma unroll
    for (int i = 0; i < 4; i++) af[i]  = *(const bf16x8*)&As[cur][(wr * 64 + i * 16 + l16) * 32 + l8];
#pragma unroll
    for (int j = 0; j < 4; j++) bfr[j] = *(const bf16x8*)&Bs[cur][(wc * 64 + j * 16 + l16) * 32 + l8];
#pragma unroll
    for (int i = 0; i < 4; i++)
#pragma unroll
      for (int j = 0; j < 4; j++)
        acc[i][j] = __builtin_amdgcn_mfma_f32_16x16x32_bf16(af[i], bfr[j], acc[i][j], 0, 0, 0);
  }

#pragma unroll
  for (int i = 0; i < 4; i++) {
    int rbase = M0 + wr * 64 + i * 16 + (lane >> 4) * 4;
#pragma unroll
    for (int j = 0; j < 4; j++) {
      int col = N0 + wc * 64 + j * 16 + l16;
      float bb = bout[col];
#pragma unroll
      for (int p = 0; p < 4; p++) {
        int row = rbase + p;
        out[(size_t)row * 512 + col] = acc[i][j][p] + bb;
      }
    }
  }
}

// ================= launch =====================================================
extern "C" void kernel_launch(void* const* d_in, const int* in_sizes, int n_in,
                              void* d_out, int out_size, void* d_ws, size_t ws_size,
                              hipStream_t stream)
{
  const float* x    = (const float*)d_in[0];
  const float* wqkv = (const float*)d_in[1];
  const float* rpb  = (const float*)d_in[2];
  const float* sita = (const float*)d_in[3];
  const float* wout = (const float*)d_in[4];
  const float* bout = (const float*)d_in[5];
  const float* dis  = (const float*)d_in[6];
  const int*   rpi  = (const int*)d_in[7];

  float* out    = (float*)d_out;                 // [8,1024,512]
  float* qkvcat = out + 4194304;                 // [8,8,1024,192]
  float* sm0    = out + 16777216;                // [8,8,1024,1024]

  char* ws = (char*)d_ws;
  unsigned short* xb   = (unsigned short*)(ws + WS_XB);
  unsigned short* wqt  = (unsigned short*)(ws + WS_WQT);
  unsigned short* wot  = (unsigned short*)(ws + WS_WOT);
  unsigned short* qbp  = (unsigned short*)(ws + WS_QB);
  unsigned short* kbp  = (unsigned short*)(ws + WS_KB);
  unsigned short* vtp  = (unsigned short*)(ws + WS_VT);
  unsigned short* bias = (unsigned short*)(ws + WS_BIAS);
  unsigned short* oa   = (unsigned short*)(ws + WS_OA);  // holds V row-major first

  prep_kernel<<<8192, 256, 0, stream>>>(x, wqkv, wout, xb, wqt, wot);
  bias_kernel<<<8192, 256, 0, stream>>>(rpb, sita, dis, rpi, bias);
  qkv_gemm<<<768, 256, 0, stream>>>(xb, wqt, qkvcat, qbp, kbp, oa /*V row-major*/);
  vtrans_kernel<<<1024, 256, 0, stream>>>(oa, vtp);
  hipFuncSetAttribute((const void*)attn_kernel,
                      hipFuncAttributeMaxDynamicSharedMemorySize, ATTN_SMEM);
  attn_kernel<<<2048, 512, ATTN_SMEM, stream>>>(qbp, kbp, vtp, bias, sm0, oa);
  out_gemm<<<256, 256, 0, stream>>>(oa, wot, bout, out);
}